// Round 7
// baseline (1432.772 us; speedup 1.0000x reference)
//
#include <hip/hip_runtime.h>
#include <hip/hip_bf16.h>

#define N_NODES 100000
#define N_EDGES 600000
#define HID 128
#define OUT_DIM 256
#define N_GRAPHS 256
#define BN 32            // nodes per block in fused SAGE kernel
#define LDA2 132         // smA row stride in floats
#define SCAN_B 512
#define SCAN_NB ((N_NODES + SCAN_B) / SCAN_B)

typedef __attribute__((ext_vector_type(8))) __bf16 bf16x8;
typedef __attribute__((ext_vector_type(4))) float f32x4;

__device__ inline f32x4 mfma16(bf16x8 a, bf16x8 b, f32x4 c) {
    return __builtin_amdgcn_mfma_f32_16x16x32_bf16(a, b, c, 0, 0, 0);
}

__device__ inline unsigned short bf_bits(__bf16 b) {
    union { __bf16 b; unsigned short u; } x; x.b = b; return x.u;
}

// ---------------- degree count ----------------
__global__ void count_kernel(const int* __restrict__ dst, int* __restrict__ deg) {
    int e = blockIdx.x * blockDim.x + threadIdx.x;
    if (e < N_EDGES) atomicAdd(&deg[dst[e]], 1);
}

// ---------------- block-level exclusive scan ----------------
__global__ __launch_bounds__(SCAN_B) void scan1_kernel(
    const int* __restrict__ deg, int* __restrict__ part, int* __restrict__ bsum)
{
    __shared__ int s[SCAN_B];
    int t = threadIdx.x;
    int i = blockIdx.x * SCAN_B + t;
    int v = (i < N_NODES) ? deg[i] : 0;
    s[t] = v;
    __syncthreads();
    #pragma unroll
    for (int off = 1; off < SCAN_B; off <<= 1) {
        int x = (t >= off) ? s[t - off] : 0;
        __syncthreads();
        s[t] += x;
        __syncthreads();
    }
    part[i] = s[t] - v;
    if (t == SCAN_B - 1) bsum[blockIdx.x] = s[t];
}

__global__ __launch_bounds__(256) void scan2_kernel(
    const int* __restrict__ bsum, int* __restrict__ boff)
{
    __shared__ int s[256];
    int t = threadIdx.x;
    int v = (t < SCAN_NB) ? bsum[t] : 0;
    s[t] = v;
    __syncthreads();
    #pragma unroll
    for (int off = 1; off < 256; off <<= 1) {
        int x = (t >= off) ? s[t - off] : 0;
        __syncthreads();
        s[t] += x;
        __syncthreads();
    }
    if (t < SCAN_NB) boff[t] = s[t] - v;
}

__global__ __launch_bounds__(SCAN_B) void scan3_kernel(
    const int* __restrict__ part, const int* __restrict__ boff,
    const int* __restrict__ deg,
    int* __restrict__ row_ptr, int* __restrict__ cursor, float* __restrict__ invdeg)
{
    int i = blockIdx.x * SCAN_B + threadIdx.x;
    int rp = part[i] + boff[blockIdx.x];
    if (i <= N_NODES) row_ptr[i] = rp;
    if (i < N_NODES) {
        cursor[i] = rp;
        invdeg[i] = 1.0f / (float)max(deg[i], 1);
    }
}

// fill CSR; also zero the pool accumulators (needed before layer-3's fused pool)
__global__ void fill_kernel(const int* __restrict__ src, const int* __restrict__ dst,
                            int* __restrict__ cursor, int* __restrict__ csr_src,
                            float* __restrict__ gsum, float* __restrict__ gmax,
                            float* __restrict__ gcnt)
{
    int e = blockIdx.x * blockDim.x + threadIdx.x;
    if (e < N_GRAPHS * HID) { gsum[e] = 0.f; gmax[e] = 0.f; }
    if (e < N_GRAPHS) gcnt[e] = 0.f;
    if (e < N_EDGES) {
        int t = dst[e];
        int pos = atomicAdd(&cursor[t], 1);
        csr_src[pos] = src[e];
    }
}

// ---------------- weight prep: stacked [Wl;Wr] -> fragment-major bf16 hi/lo ----------------
__global__ __launch_bounds__(256) void prep_w_all(
    const float* __restrict__ W1l, const float* __restrict__ W1r,
    const float* __restrict__ W2l, const float* __restrict__ W2r,
    const float* __restrict__ W3l, const float* __restrict__ W3r,
    unsigned short* __restrict__ wf1, unsigned short* __restrict__ wf2,
    unsigned short* __restrict__ wf3)
{
    int set = blockIdx.x >> 7;
    const float* Wl = (set == 0) ? W1l : (set == 1) ? W2l : W3l;
    const float* Wr = (set == 0) ? W1r : (set == 1) ? W2r : W3r;
    unsigned short* wf = (set == 0) ? wf1 : (set == 1) ? wf2 : wf3;

    int flat = (blockIdx.x & 127) * 256 + threadIdx.x;   // 32768 per set
    int j  = flat & 7;
    int l  = (flat >> 3) & 63;
    int nf = (flat >> 9) & 7;
    int ks = flat >> 12;
    int k = ks * 32 + ((l >> 4) << 3) + j;
    int c = nf * 16 + (l & 15);
    float v = (k < HID) ? Wl[k * HID + c] : Wr[(k - HID) * HID + c];
    __bf16 hi = (__bf16)v;
    __bf16 lo = (__bf16)(v - (float)hi);
    wf[flat]         = bf_bits(hi);
    wf[32768 + flat] = bf_bits(lo);
}

// ---------------- fused gather + split-bf16 MFMA GEMM + LayerNorm + ReLU (+pool) ----------------
template<bool LAST>
__global__ __launch_bounds__(256, 8) void sage_mfma(
    const float* __restrict__ h_in,
    const int* __restrict__ row_ptr, const int* __restrict__ csr_src,
    const float* __restrict__ invdeg,
    const unsigned short* __restrict__ wf,
    const float* __restrict__ bias, const float* __restrict__ gamma,
    const float* __restrict__ beta,
    float* __restrict__ h_out,
    const int* __restrict__ gb,
    float* __restrict__ gsum, float* __restrict__ gmax, float* __restrict__ gcnt)
{
    __shared__ float smA[BN * LDA2];         // 16.9 KB: agg sums -> means -> (LAST) post-LN values
    __shared__ float lnred[BN][4][2];
    __shared__ int rp_lds[BN + 1];
    __shared__ int gbs[BN];

    const int tid  = threadIdx.x;
    const int lane = tid & 63;
    const int w    = tid >> 6;
    const int lq   = lane & 15;
    const int lg   = lane >> 4;
    const int node0 = blockIdx.x * BN;

    // ---- zero agg region + stage row_ptr (+ graph ids) ----
    {
        int n = tid >> 3, q = tid & 7;
        f32x4 z = {0.f, 0.f, 0.f, 0.f};
        float* p = &smA[n * LDA2 + q * 16];
        *(f32x4*)(p + 0)  = z;
        *(f32x4*)(p + 4)  = z;
        *(f32x4*)(p + 8)  = z;
        *(f32x4*)(p + 12) = z;
    }
    if (tid < BN + 1) rp_lds[tid] = row_ptr[node0 + tid];
    if (LAST && tid < BN) gbs[tid] = gb[node0 + tid];
    __syncthreads();

    const int e0 = rp_lds[0];
    const int E  = rp_lds[BN] - e0;

    // ---- edge-parallel gather: half-wave per edge, fire-and-forget LDS atomics ----
    // Edge slot p = hw + 8*t (t = hl + 32*r). No accumulator chains: every edge is an
    // independent {row load -> 4x ds_add_f32} so loads pipeline freely.
    {
        const int hw  = tid >> 5;            // half-wave id 0..7
        const int hl  = tid & 31;
        const int rot = (hl >> 3) & 3;       // j-rotation kills the 4-way LDS bank conflict
        const int d0  = hl << 2;

        for (int r = 0; hw + (r << 8) < E; ++r) {
            int p_lane = hw + ((hl + (r << 5)) << 3);
            int e_lane = e0 + min(p_lane, E - 1);
            int idx_lane = csr_src[e_lane];
            int lo = 0, hi = BN;             // find n: rp[n] <= e_lane < rp[n+1]
            #pragma unroll
            for (int it = 0; it < 5; ++it) {
                int mid = (lo + hi) >> 1;
                bool ge = (e_lane >= rp_lds[mid]);
                lo = ge ? mid : lo;
                hi = ge ? hi : mid;
            }
            int n_lane = lo;
            int nt = min(32, ((E - hw - (r << 8)) + 7) >> 3);
            #pragma unroll 4
            for (int tt = 0; tt < nt; ++tt) {
                int i = __shfl(idx_lane, tt, 32);
                int n = __shfl(n_lane, tt, 32);
                f32x4 v = *(const f32x4*)(h_in + (size_t)i * HID + d0);
                float* pa = &smA[n * LDA2 + d0];
                #pragma unroll
                for (int j = 0; j < 4; ++j) {
                    int jj = (j + rot) & 3;
                    atomicAdd(pa + jj, v[jj]);
                }
            }
        }
    }
    __syncthreads();

    // ---- divide by degree (mean) ----
    {
        int n = tid >> 3, q = tid & 7;
        float inv = invdeg[node0 + n];
        float* p = &smA[n * LDA2 + q * 16];
        #pragma unroll
        for (int j = 0; j < 4; ++j) {
            f32x4 v = *(f32x4*)(p + j * 4);
            v *= inv;
            *(f32x4*)(p + j * 4) = v;
        }
    }
    __syncthreads();

    // ---- split-bf16 MFMA GEMM: out[32 x 128] = [agg|root][32 x 256] @ W[256 x 128] ----
    const int nf0 = w * 2;
    const int col0 = nf0 * 16 + lq;          // = w*32 + lq
    const int col1 = col0 + 16;

    f32x4 acc[2][2];
    {
        float b0 = bias[col0], b1 = bias[col1];
        #pragma unroll
        for (int m = 0; m < 2; ++m) {
            acc[m][0] = (f32x4){b0, b0, b0, b0};
            acc[m][1] = (f32x4){b1, b1, b1, b1};
        }
    }

    const bf16x8* wfv = (const bf16x8*)wf;
    #pragma unroll 2
    for (int ks = 0; ks < 8; ++ks) {
        int base = (ks << 9) + nf0 * 64 + lane;      // ushort8 units
        bf16x8 bh0 = wfv[base];
        bf16x8 bh1 = wfv[base + 64];
        bf16x8 bl0 = wfv[base + 4096];
        bf16x8 bl1 = wfv[base + 4096 + 64];
        #pragma unroll
        for (int m = 0; m < 2; ++m) {
            float4 a0, a1;
            if (ks < 4) {
                const float* ap = &smA[(m * 16 + lq) * LDA2 + (ks << 5) + (lg << 3)];
                a0 = *(const float4*)ap;
                a1 = *(const float4*)(ap + 4);
            } else {
                const float* rp = h_in + (size_t)(node0 + m * 16 + lq) * HID
                                + ((ks - 4) << 5) + (lg << 3);
                a0 = *(const float4*)rp;
                a1 = *(const float4*)(rp + 4);
            }
            float av[8] = {a0.x, a0.y, a0.z, a0.w, a1.x, a1.y, a1.z, a1.w};
            bf16x8 ahi, alo;
            #pragma unroll
            for (int j = 0; j < 8; ++j) {
                __bf16 h = (__bf16)av[j];
                ahi[j] = h;
                alo[j] = (__bf16)(av[j] - (float)h);
            }
            acc[m][0] = mfma16(ahi, bh0, acc[m][0]);
            acc[m][0] = mfma16(alo, bh0, acc[m][0]);
            acc[m][0] = mfma16(ahi, bl0, acc[m][0]);
            acc[m][1] = mfma16(ahi, bh1, acc[m][1]);
            acc[m][1] = mfma16(alo, bh1, acc[m][1]);
            acc[m][1] = mfma16(ahi, bl1, acc[m][1]);
        }
    }

    // ---- LayerNorm partials: value (m, r) sits at node m*16+lg*4+r ----
    #pragma unroll
    for (int m = 0; m < 2; ++m) {
        #pragma unroll
        for (int r = 0; r < 4; ++r) {
            float pv = acc[m][0][r] + acc[m][1][r];
            float qv = acc[m][0][r] * acc[m][0][r] + acc[m][1][r] * acc[m][1][r];
            #pragma unroll
            for (int off = 8; off >= 1; off >>= 1) {
                pv += __shfl_xor(pv, off, 64);
                qv += __shfl_xor(qv, off, 64);
            }
            if (lq == 0) {
                int n = m * 16 + lg * 4 + r;
                lnred[n][w][0] = pv;
                lnred[n][w][1] = qv;
            }
        }
    }
    __syncthreads();   // also guarantees all smA (agg) reads are done

    // ---- finalize LN + ReLU; store to global (layers 1,2) or LDS (layer 3) ----
    float g0 = gamma[col0], g1 = gamma[col1];
    float be0 = beta[col0], be1 = beta[col1];
    #pragma unroll
    for (int m = 0; m < 2; ++m) {
        #pragma unroll
        for (int r = 0; r < 4; ++r) {
            int n = m * 16 + lg * 4 + r;
            float p = lnred[n][0][0] + lnred[n][1][0] + lnred[n][2][0] + lnred[n][3][0];
            float q = lnred[n][0][1] + lnred[n][1][1] + lnred[n][2][1] + lnred[n][3][1];
            float mu  = p * (1.0f / HID);
            float var = q * (1.0f / HID) - mu * mu;
            float rs = rsqrtf(var + 1e-5f);
            float o0 = fmaxf((acc[m][0][r] - mu) * rs * g0 + be0, 0.f);
            float o1 = fmaxf((acc[m][1][r] - mu) * rs * g1 + be1, 0.f);
            if (LAST) {
                smA[n * LDA2 + col0] = o0;
                smA[n * LDA2 + col1] = o1;
            } else {
                int node = node0 + n;
                h_out[(size_t)node * HID + col0] = o0;
                h_out[(size_t)node * HID + col1] = o1;
            }
        }
    }

    if (LAST) {
        __syncthreads();
        // block-level segmented mean/max pool over the 32 sorted nodes
        int colp = tid & 127;
        int nst = (tid >> 7) * 16, nen = nst + 16;
        int curg = gbs[nst];
        float s = 0.f, mx = 0.f;
        int c = 0;
        for (int n2 = nst; n2 < nen; ++n2) {
            int g = gbs[n2];
            if (g != curg) {
                atomicAdd(&gsum[curg * HID + colp], s);
                atomicMax((int*)&gmax[curg * HID + colp], __float_as_int(mx));
                if (colp == 0) atomicAdd(&gcnt[curg], (float)c);
                curg = g; s = 0.f; mx = 0.f; c = 0;
            }
            float v = smA[n2 * LDA2 + colp];
            s += v;
            mx = fmaxf(mx, v);   // post-ReLU: v >= 0, init 0 safe
            ++c;
        }
        atomicAdd(&gsum[curg * HID + colp], s);
        atomicMax((int*)&gmax[curg * HID + colp], __float_as_int(mx));
        if (colp == 0) atomicAdd(&gcnt[curg], (float)c);
    }
}

// ---------------- readout MLP + L2 normalize ----------------
__global__ __launch_bounds__(256) void readout_kernel(
    const float* __restrict__ gsum, const float* __restrict__ gmax,
    const float* __restrict__ gcnt,
    const float* __restrict__ Wr1, const float* __restrict__ br1,
    const float* __restrict__ Wr2, const float* __restrict__ br2,
    float* __restrict__ out)
{
    __shared__ float pooled[2 * HID];
    __shared__ float hid[HID];
    __shared__ float red[4];

    int g = blockIdx.x, tid = threadIdx.x;

    if (tid < HID) {
        float n = fmaxf(gcnt[g], 1.0f);
        pooled[tid] = gsum[g * HID + tid] / n;
    } else {
        pooled[tid] = gmax[g * HID + (tid - HID)];
    }
    __syncthreads();

    if (tid < HID) {
        float a = br1[tid];
        for (int k = 0; k < 2 * HID; ++k)
            a += pooled[k] * Wr1[k * HID + tid];
        hid[tid] = fmaxf(a, 0.0f);
    }
    __syncthreads();

    float a = br2[tid];
    for (int k = 0; k < HID; ++k)
        a += hid[k] * Wr2[k * OUT_DIM + tid];

    float ss = a * a;
    #pragma unroll
    for (int off = 32; off >= 1; off >>= 1) ss += __shfl_xor(ss, off, 64);
    int wv = tid >> 6, lane = tid & 63;
    if (lane == 0) red[wv] = ss;
    __syncthreads();
    float tot = red[0] + red[1] + red[2] + red[3];
    float nrm = fmaxf(sqrtf(tot), 1e-12f);
    out[g * OUT_DIM + tid] = a / nrm;
}

extern "C" void kernel_launch(void* const* d_in, const int* in_sizes, int n_in,
                              void* d_out, int out_size, void* d_ws, size_t ws_size,
                              hipStream_t stream) {
    const float* x   = (const float*)d_in[0];
    const int*   ei  = (const int*)d_in[1];
    const int*   gb  = (const int*)d_in[2];
    const float* W1l = (const float*)d_in[3];
    const float* W1r = (const float*)d_in[4];
    const float* b1  = (const float*)d_in[5];
    const float* g1  = (const float*)d_in[6];
    const float* be1 = (const float*)d_in[7];
    const float* W2l = (const float*)d_in[8];
    const float* W2r = (const float*)d_in[9];
    const float* b2  = (const float*)d_in[10];
    const float* g2  = (const float*)d_in[11];
    const float* be2 = (const float*)d_in[12];
    const float* W3l = (const float*)d_in[13];
    const float* W3r = (const float*)d_in[14];
    const float* b3  = (const float*)d_in[15];
    const float* g3  = (const float*)d_in[16];
    const float* be3 = (const float*)d_in[17];
    const float* Wr1 = (const float*)d_in[18];
    const float* br1 = (const float*)d_in[19];
    const float* Wr2 = (const float*)d_in[20];
    const float* br2 = (const float*)d_in[21];

    const int* src = ei;
    const int* dst = ei + N_EDGES;

    char* ws = (char*)d_ws;
    size_t off = 0;
    auto alloc = [&](size_t bytes) -> void* {
        void* p = ws + off;
        off += (bytes + 255) & ~(size_t)255;
        return p;
    };
    float* hA      = (float*)alloc((size_t)N_NODES * HID * 4);
    float* hB      = (float*)alloc((size_t)N_NODES * HID * 4);
    int*   deg     = (int*)alloc((size_t)N_NODES * 4);
    int*   part    = (int*)alloc((size_t)SCAN_NB * SCAN_B * 4);
    int*   bsum    = (int*)alloc((size_t)SCAN_NB * 4);
    int*   boff    = (int*)alloc((size_t)SCAN_NB * 4);
    int*   row_ptr = (int*)alloc((size_t)(N_NODES + 1) * 4);
    int*   cursor  = (int*)alloc((size_t)N_NODES * 4);
    float* invdeg  = (float*)alloc((size_t)N_NODES * 4);
    int*   csr_src = (int*)alloc((size_t)N_EDGES * 4);
    float* gsum    = (float*)alloc((size_t)N_GRAPHS * HID * 4);
    float* gmax    = (float*)alloc((size_t)N_GRAPHS * HID * 4);
    float* gcnt    = (float*)alloc((size_t)N_GRAPHS * 4);
    unsigned short* wf1 = (unsigned short*)alloc(65536 * 2);
    unsigned short* wf2 = (unsigned short*)alloc(65536 * 2);
    unsigned short* wf3 = (unsigned short*)alloc(65536 * 2);

    // ---- build CSR (once) + weight prep + pool-buffer zeroing ----
    hipMemsetAsync(deg, 0, (size_t)N_NODES * 4, stream);
    count_kernel<<<(N_EDGES + 255) / 256, 256, 0, stream>>>(dst, deg);
    scan1_kernel<<<SCAN_NB, SCAN_B, 0, stream>>>(deg, part, bsum);
    scan2_kernel<<<1, 256, 0, stream>>>(bsum, boff);
    scan3_kernel<<<SCAN_NB, SCAN_B, 0, stream>>>(part, boff, deg, row_ptr, cursor, invdeg);
    fill_kernel<<<(N_EDGES + 255) / 256, 256, 0, stream>>>(src, dst, cursor, csr_src,
                                                           gsum, gmax, gcnt);
    prep_w_all<<<384, 256, 0, stream>>>(W1l, W1r, W2l, W2r, W3l, W3r, wf1, wf2, wf3);

    const int sage_blocks = N_NODES / BN;   // 3125, exact

    // ---- 3 fused SAGE layers (layer 3 fuses the pool) ----
    sage_mfma<false><<<sage_blocks, 256, 0, stream>>>(x,  row_ptr, csr_src, invdeg, wf1,
                                                      b1, g1, be1, hA, gb, gsum, gmax, gcnt);
    sage_mfma<false><<<sage_blocks, 256, 0, stream>>>(hA, row_ptr, csr_src, invdeg, wf2,
                                                      b2, g2, be2, hB, gb, gsum, gmax, gcnt);
    sage_mfma<true><<<sage_blocks, 256, 0, stream>>>(hB, row_ptr, csr_src, invdeg, wf3,
                                                     b3, g3, be3, hA, gb, gsum, gmax, gcnt);

    // ---- readout ----
    readout_kernel<<<N_GRAPHS, 256, 0, stream>>>(gsum, gmax, gcnt, Wr1, br1, Wr2, br2, (float*)d_out);
}

// Round 10
// 348.383 us; speedup vs baseline: 4.1126x; 4.1126x over previous
//
#include <hip/hip_runtime.h>
#include <hip/hip_bf16.h>

#define N_NODES 100000
#define N_EDGES 600000
#define HID 128
#define OUT_DIM 256
#define N_GRAPHS 256
#define BN 32            // nodes per block in fused SAGE kernel
#define LDA2 132         // smA row stride in floats
#define SCAN_B 512
#define SCAN_NB ((N_NODES + SCAN_B) / SCAN_B)

typedef __attribute__((ext_vector_type(8))) __bf16 bf16x8;
typedef __attribute__((ext_vector_type(4))) float f32x4;

__device__ inline f32x4 mfma16(bf16x8 a, bf16x8 b, f32x4 c) {
    return __builtin_amdgcn_mfma_f32_16x16x32_bf16(a, b, c, 0, 0, 0);
}

__device__ inline unsigned short bf_bits(__bf16 b) {
    union { __bf16 b; unsigned short u; } x; x.b = b; return x.u;
}

// ---------------- degree count ----------------
__global__ void count_kernel(const int* __restrict__ dst, int* __restrict__ deg) {
    int e = blockIdx.x * blockDim.x + threadIdx.x;
    if (e < N_EDGES) atomicAdd(&deg[dst[e]], 1);
}

// ---------------- block-level exclusive scan ----------------
__global__ __launch_bounds__(SCAN_B) void scan1_kernel(
    const int* __restrict__ deg, int* __restrict__ part, int* __restrict__ bsum)
{
    __shared__ int s[SCAN_B];
    int t = threadIdx.x;
    int i = blockIdx.x * SCAN_B + t;
    int v = (i < N_NODES) ? deg[i] : 0;
    s[t] = v;
    __syncthreads();
    #pragma unroll
    for (int off = 1; off < SCAN_B; off <<= 1) {
        int x = (t >= off) ? s[t - off] : 0;
        __syncthreads();
        s[t] += x;
        __syncthreads();
    }
    part[i] = s[t] - v;
    if (t == SCAN_B - 1) bsum[blockIdx.x] = s[t];
}

__global__ __launch_bounds__(256) void scan2_kernel(
    const int* __restrict__ bsum, int* __restrict__ boff)
{
    __shared__ int s[256];
    int t = threadIdx.x;
    int v = (t < SCAN_NB) ? bsum[t] : 0;
    s[t] = v;
    __syncthreads();
    #pragma unroll
    for (int off = 1; off < 256; off <<= 1) {
        int x = (t >= off) ? s[t - off] : 0;
        __syncthreads();
        s[t] += x;
        __syncthreads();
    }
    if (t < SCAN_NB) boff[t] = s[t] - v;
}

__global__ __launch_bounds__(SCAN_B) void scan3_kernel(
    const int* __restrict__ part, const int* __restrict__ boff,
    const int* __restrict__ deg,
    int* __restrict__ row_ptr, int* __restrict__ cursor, float* __restrict__ invdeg)
{
    int i = blockIdx.x * SCAN_B + threadIdx.x;
    int rp = part[i] + boff[blockIdx.x];
    if (i <= N_NODES) row_ptr[i] = rp;
    if (i < N_NODES) {
        cursor[i] = rp;
        invdeg[i] = 1.0f / (float)max(deg[i], 1);
    }
}

// fill CSR; also zero the pool accumulators (needed before layer-3's fused pool)
__global__ void fill_kernel(const int* __restrict__ src, const int* __restrict__ dst,
                            int* __restrict__ cursor, int* __restrict__ csr_src,
                            float* __restrict__ gsum, float* __restrict__ gmax,
                            float* __restrict__ gcnt)
{
    int e = blockIdx.x * blockDim.x + threadIdx.x;
    if (e < N_GRAPHS * HID) { gsum[e] = 0.f; gmax[e] = 0.f; }
    if (e < N_GRAPHS) gcnt[e] = 0.f;
    if (e < N_EDGES) {
        int t = dst[e];
        int pos = atomicAdd(&cursor[t], 1);
        csr_src[pos] = src[e];
    }
}

// ---------------- weight prep: stacked [Wl;Wr] -> fragment-major bf16 hi/lo ----------------
__global__ __launch_bounds__(256) void prep_w_all(
    const float* __restrict__ W1l, const float* __restrict__ W1r,
    const float* __restrict__ W2l, const float* __restrict__ W2r,
    const float* __restrict__ W3l, const float* __restrict__ W3r,
    unsigned short* __restrict__ wf1, unsigned short* __restrict__ wf2,
    unsigned short* __restrict__ wf3)
{
    int set = blockIdx.x >> 7;
    const float* Wl = (set == 0) ? W1l : (set == 1) ? W2l : W3l;
    const float* Wr = (set == 0) ? W1r : (set == 1) ? W2r : W3r;
    unsigned short* wf = (set == 0) ? wf1 : (set == 1) ? wf2 : wf3;

    int flat = (blockIdx.x & 127) * 256 + threadIdx.x;   // 32768 per set
    int j  = flat & 7;
    int l  = (flat >> 3) & 63;
    int nf = (flat >> 9) & 7;
    int ks = flat >> 12;
    int k = ks * 32 + ((l >> 4) << 3) + j;
    int c = nf * 16 + (l & 15);
    float v = (k < HID) ? Wl[k * HID + c] : Wr[(k - HID) * HID + c];
    __bf16 hi = (__bf16)v;
    __bf16 lo = (__bf16)(v - (float)hi);
    wf[flat]         = bf_bits(hi);
    wf[32768 + flat] = bf_bits(lo);
}

// ---------------- fused gather + split-bf16 MFMA GEMM + LayerNorm + ReLU (+pool) ----------------
template<bool LAST>
__global__ __launch_bounds__(256, 8) void sage_mfma(
    const float* __restrict__ h_in,
    const int* __restrict__ row_ptr, const int* __restrict__ csr_src,
    const float* __restrict__ invdeg,
    const unsigned short* __restrict__ wf,
    const float* __restrict__ bias, const float* __restrict__ gamma,
    const float* __restrict__ beta,
    float* __restrict__ h_out,
    const int* __restrict__ gb,
    float* __restrict__ gsum, float* __restrict__ gmax, float* __restrict__ gcnt)
{
    __shared__ float smA[BN * LDA2];         // 16.9 KB: agg means -> (LAST) post-LN values
    __shared__ float lnred[BN][4][2];
    __shared__ int gbs[BN];

    const int tid  = threadIdx.x;
    const int lane = tid & 63;
    const int w    = tid >> 6;
    const int lq   = lane & 15;
    const int lg   = lane >> 4;
    const int node0 = blockIdx.x * BN;

    if (LAST && tid < BN) gbs[tid] = gb[node0 + tid];

    // ---- gather neighbor mean into smA[n][0..127] ----
    // half-wave per node (32 lanes x f32x4 = full 512B row per edge); the half-wave's
    // 4 nodes processed with hoisted index setup (4 independent index chains in flight).
    // VERIFIED structure (round-6 bench, absmax 2^-10): loads only issued for valid slots.
    {
        const int hw = tid >> 5;             // half-wave id 0..7
        const int hl = tid & 31;
        const int d0 = hl << 2;

        int r0a[4], dga[4], idxa[4];
        float inva[4];
        #pragma unroll
        for (int i = 0; i < 4; ++i) {
            int node = node0 + hw * 4 + i;
            int rp0 = row_ptr[node];
            int rp1 = row_ptr[node + 1];
            r0a[i] = rp0;
            dga[i] = rp1 - rp0;
            idxa[i] = csr_src[min(rp0 + hl, N_EDGES - 1)];
            inva[i] = invdeg[node];
        }

        #pragma unroll
        for (int i = 0; i < 4; ++i) {
            int n = hw * 4 + i;
            int deg = dga[i];
            int dc = min(deg, 32);
            f32x4 a0 = {0.f, 0.f, 0.f, 0.f}, a1 = a0, a2 = a0, a3 = a0;
            int s = 0;
            for (; s + 3 < dc; s += 4) {     // 4 independent loads per step
                int i0 = __shfl(idxa[i], s,     32);
                int i1 = __shfl(idxa[i], s + 1, 32);
                int i2 = __shfl(idxa[i], s + 2, 32);
                int i3 = __shfl(idxa[i], s + 3, 32);
                a0 += *(const f32x4*)(h_in + (size_t)i0 * HID + d0);
                a1 += *(const f32x4*)(h_in + (size_t)i1 * HID + d0);
                a2 += *(const f32x4*)(h_in + (size_t)i2 * HID + d0);
                a3 += *(const f32x4*)(h_in + (size_t)i3 * HID + d0);
            }
            if (s < dc) {                     // tail 1..3, rotating accumulators
                int i0 = __shfl(idxa[i], s, 32);
                a0 += *(const f32x4*)(h_in + (size_t)i0 * HID + d0);
                if (s + 1 < dc) {
                    int i1 = __shfl(idxa[i], s + 1, 32);
                    a1 += *(const f32x4*)(h_in + (size_t)i1 * HID + d0);
                }
                if (s + 2 < dc) {
                    int i2 = __shfl(idxa[i], s + 2, 32);
                    a2 += *(const f32x4*)(h_in + (size_t)i2 * HID + d0);
                }
            }
            for (int t2 = 32; t2 < deg; ++t2) {   // P(deg>32) ~ 1e-12
                int i0 = csr_src[r0a[i] + t2];
                a0 += *(const f32x4*)(h_in + (size_t)i0 * HID + d0);
            }
            f32x4 a = (a0 + a1) + (a2 + a3);
            a *= inva[i];
            *(f32x4*)&smA[n * LDA2 + d0] = a;
        }
    }
    __syncthreads();

    // ---- split-bf16 MFMA GEMM: out[32 x 128] = [agg|root][32 x 256] @ W[256 x 128] ----
    // agg half (ks 0..3) from LDS; root half (ks 4..7) straight from global.
    // FULL 4-term product (ahi+alo)(bhi+blo): per-product error ~2^-18 relative.
    const int nf0 = w * 2;
    const int col0 = nf0 * 16 + lq;          // = w*32 + lq
    const int col1 = col0 + 16;

    f32x4 acc[2][2];
    {
        float b0 = bias[col0], b1 = bias[col1];
        #pragma unroll
        for (int m = 0; m < 2; ++m) {
            acc[m][0] = (f32x4){b0, b0, b0, b0};
            acc[m][1] = (f32x4){b1, b1, b1, b1};
        }
    }

    const bf16x8* wfv = (const bf16x8*)wf;
    #pragma unroll 2
    for (int ks = 0; ks < 8; ++ks) {
        int base = (ks << 9) + nf0 * 64 + lane;      // ushort8 units
        bf16x8 bh0 = wfv[base];
        bf16x8 bh1 = wfv[base + 64];
        bf16x8 bl0 = wfv[base + 4096];
        bf16x8 bl1 = wfv[base + 4096 + 64];
        #pragma unroll
        for (int m = 0; m < 2; ++m) {
            float4 a0, a1;
            if (ks < 4) {
                const float* ap = &smA[(m * 16 + lq) * LDA2 + (ks << 5) + (lg << 3)];
                a0 = *(const float4*)ap;
                a1 = *(const float4*)(ap + 4);
            } else {
                const float* rp = h_in + (size_t)(node0 + m * 16 + lq) * HID
                                + ((ks - 4) << 5) + (lg << 3);
                a0 = *(const float4*)rp;
                a1 = *(const float4*)(rp + 4);
            }
            float av[8] = {a0.x, a0.y, a0.z, a0.w, a1.x, a1.y, a1.z, a1.w};
            bf16x8 ahi, alo;
            #pragma unroll
            for (int j = 0; j < 8; ++j) {
                __bf16 h = (__bf16)av[j];
                ahi[j] = h;
                alo[j] = (__bf16)(av[j] - (float)h);
            }
            acc[m][0] = mfma16(ahi, bh0, acc[m][0]);
            acc[m][0] = mfma16(alo, bh0, acc[m][0]);
            acc[m][0] = mfma16(ahi, bl0, acc[m][0]);
            acc[m][0] = mfma16(alo, bl0, acc[m][0]);
            acc[m][1] = mfma16(ahi, bh1, acc[m][1]);
            acc[m][1] = mfma16(alo, bh1, acc[m][1]);
            acc[m][1] = mfma16(ahi, bl1, acc[m][1]);
            acc[m][1] = mfma16(alo, bl1, acc[m][1]);
        }
    }

    // ---- LayerNorm partials: value (m, r) sits at node m*16+lg*4+r ----
    #pragma unroll
    for (int m = 0; m < 2; ++m) {
        #pragma unroll
        for (int r = 0; r < 4; ++r) {
            float pv = acc[m][0][r] + acc[m][1][r];
            float qv = acc[m][0][r] * acc[m][0][r] + acc[m][1][r] * acc[m][1][r];
            #pragma unroll
            for (int off = 8; off >= 1; off >>= 1) {
                pv += __shfl_xor(pv, off, 64);
                qv += __shfl_xor(qv, off, 64);
            }
            if (lq == 0) {
                int n = m * 16 + lg * 4 + r;
                lnred[n][w][0] = pv;
                lnred[n][w][1] = qv;
            }
        }
    }
    __syncthreads();   // also guarantees all smA (agg) reads are done

    // ---- finalize LN + ReLU; store to global (layers 1,2) or LDS (layer 3) ----
    float g0 = gamma[col0], g1 = gamma[col1];
    float be0 = beta[col0], be1 = beta[col1];
    #pragma unroll
    for (int m = 0; m < 2; ++m) {
        #pragma unroll
        for (int r = 0; r < 4; ++r) {
            int n = m * 16 + lg * 4 + r;
            float p = lnred[n][0][0] + lnred[n][1][0] + lnred[n][2][0] + lnred[n][3][0];
            float q = lnred[n][0][1] + lnred[n][1][1] + lnred[n][2][1] + lnred[n][3][1];
            float mu  = p * (1.0f / HID);
            float var = q * (1.0f / HID) - mu * mu;
            // Newton-refined rsqrt: v_rsq_f32 is ~2^-12 approx; one step -> ~2^-23
            float xv = var + 1e-5f;
            float rs = rsqrtf(xv);
            rs = rs * (1.5f - 0.5f * xv * rs * rs);
            float o0 = fmaxf((acc[m][0][r] - mu) * rs * g0 + be0, 0.f);
            float o1 = fmaxf((acc[m][1][r] - mu) * rs * g1 + be1, 0.f);
            if (LAST) {
                smA[n * LDA2 + col0] = o0;
                smA[n * LDA2 + col1] = o1;
            } else {
                int node = node0 + n;
                h_out[(size_t)node * HID + col0] = o0;
                h_out[(size_t)node * HID + col1] = o1;
            }
        }
    }

    if (LAST) {
        __syncthreads();
        // block-level segmented mean/max pool over the 32 sorted nodes
        int colp = tid & 127;
        int nst = (tid >> 7) * 16, nen = nst + 16;
        int curg = gbs[nst];
        float s = 0.f, mx = 0.f;
        int c = 0;
        for (int n2 = nst; n2 < nen; ++n2) {
            int g = gbs[n2];
            if (g != curg) {
                atomicAdd(&gsum[curg * HID + colp], s);
                atomicMax((int*)&gmax[curg * HID + colp], __float_as_int(mx));
                if (colp == 0) atomicAdd(&gcnt[curg], (float)c);
                curg = g; s = 0.f; mx = 0.f; c = 0;
            }
            float v = smA[n2 * LDA2 + colp];
            s += v;
            mx = fmaxf(mx, v);   // post-ReLU: v >= 0, init 0 safe
            ++c;
        }
        atomicAdd(&gsum[curg * HID + colp], s);
        atomicMax((int*)&gmax[curg * HID + colp], __float_as_int(mx));
        if (colp == 0) atomicAdd(&gcnt[curg], (float)c);
    }
}

// ---------------- readout MLP + L2 normalize ----------------
__global__ __launch_bounds__(256) void readout_kernel(
    const float* __restrict__ gsum, const float* __restrict__ gmax,
    const float* __restrict__ gcnt,
    const float* __restrict__ Wr1, const float* __restrict__ br1,
    const float* __restrict__ Wr2, const float* __restrict__ br2,
    float* __restrict__ out)
{
    __shared__ float pooled[2 * HID];
    __shared__ float hid[HID];
    __shared__ float red[4];

    int g = blockIdx.x, tid = threadIdx.x;

    if (tid < HID) {
        float n = fmaxf(gcnt[g], 1.0f);
        pooled[tid] = gsum[g * HID + tid] / n;
    } else {
        pooled[tid] = gmax[g * HID + (tid - HID)];
    }
    __syncthreads();

    if (tid < HID) {
        float a = br1[tid];
        for (int k = 0; k < 2 * HID; ++k)
            a += pooled[k] * Wr1[k * HID + tid];
        hid[tid] = fmaxf(a, 0.0f);
    }
    __syncthreads();

    float a = br2[tid];
    for (int k = 0; k < HID; ++k)
        a += hid[k] * Wr2[k * OUT_DIM + tid];

    float ss = a * a;
    #pragma unroll
    for (int off = 32; off >= 1; off >>= 1) ss += __shfl_xor(ss, off, 64);
    int wv = tid >> 6, lane = tid & 63;
    if (lane == 0) red[wv] = ss;
    __syncthreads();
    float tot = red[0] + red[1] + red[2] + red[3];
    float nrm = fmaxf(sqrtf(tot), 1e-12f);
    out[g * OUT_DIM + tid] = a / nrm;
}

extern "C" void kernel_launch(void* const* d_in, const int* in_sizes, int n_in,
                              void* d_out, int out_size, void* d_ws, size_t ws_size,
                              hipStream_t stream) {
    const float* x   = (const float*)d_in[0];
    const int*   ei  = (const int*)d_in[1];
    const int*   gb  = (const int*)d_in[2];
    const float* W1l = (const float*)d_in[3];
    const float* W1r = (const float*)d_in[4];
    const float* b1  = (const float*)d_in[5];
    const float* g1  = (const float*)d_in[6];
    const float* be1 = (const float*)d_in[7];
    const float* W2l = (const float*)d_in[8];
    const float* W2r = (const float*)d_in[9];
    const float* b2  = (const float*)d_in[10];
    const float* g2  = (const float*)d_in[11];
    const float* be2 = (const float*)d_in[12];
    const float* W3l = (const float*)d_in[13];
    const float* W3r = (const float*)d_in[14];
    const float* b3  = (const float*)d_in[15];
    const float* g3  = (const float*)d_in[16];
    const float* be3 = (const float*)d_in[17];
    const float* Wr1 = (const float*)d_in[18];
    const float* br1 = (const float*)d_in[19];
    const float* Wr2 = (const float*)d_in[20];
    const float* br2 = (const float*)d_in[21];

    const int* src = ei;
    const int* dst = ei + N_EDGES;

    char* ws = (char*)d_ws;
    size_t off = 0;
    auto alloc = [&](size_t bytes) -> void* {
        void* p = ws + off;
        off += (bytes + 255) & ~(size_t)255;
        return p;
    };
    float* hA      = (float*)alloc((size_t)N_NODES * HID * 4);
    float* hB      = (float*)alloc((size_t)N_NODES * HID * 4);
    int*   deg     = (int*)alloc((size_t)N_NODES * 4);
    int*   part    = (int*)alloc((size_t)SCAN_NB * SCAN_B * 4);
    int*   bsum    = (int*)alloc((size_t)SCAN_NB * 4);
    int*   boff    = (int*)alloc((size_t)SCAN_NB * 4);
    int*   row_ptr = (int*)alloc((size_t)(N_NODES + 1) * 4);
    int*   cursor  = (int*)alloc((size_t)N_NODES * 4);
    float* invdeg  = (float*)alloc((size_t)N_NODES * 4);
    int*   csr_src = (int*)alloc((size_t)N_EDGES * 4);
    float* gsum    = (float*)alloc((size_t)N_GRAPHS * HID * 4);
    float* gmax    = (float*)alloc((size_t)N_GRAPHS * HID * 4);
    float* gcnt    = (float*)alloc((size_t)N_GRAPHS * 4);
    unsigned short* wf1 = (unsigned short*)alloc(65536 * 2);
    unsigned short* wf2 = (unsigned short*)alloc(65536 * 2);
    unsigned short* wf3 = (unsigned short*)alloc(65536 * 2);

    // ---- build CSR (once) + weight prep + pool-buffer zeroing ----
    hipMemsetAsync(deg, 0, (size_t)N_NODES * 4, stream);
    count_kernel<<<(N_EDGES + 255) / 256, 256, 0, stream>>>(dst, deg);
    scan1_kernel<<<SCAN_NB, SCAN_B, 0, stream>>>(deg, part, bsum);
    scan2_kernel<<<1, 256, 0, stream>>>(bsum, boff);
    scan3_kernel<<<SCAN_NB, SCAN_B, 0, stream>>>(part, boff, deg, row_ptr, cursor, invdeg);
    fill_kernel<<<(N_EDGES + 255) / 256, 256, 0, stream>>>(src, dst, cursor, csr_src,
                                                           gsum, gmax, gcnt);
    prep_w_all<<<384, 256, 0, stream>>>(W1l, W1r, W2l, W2r, W3l, W3r, wf1, wf2, wf3);

    const int sage_blocks = N_NODES / BN;   // 3125, exact

    // ---- 3 fused SAGE layers (layer 3 fuses the pool) ----
    sage_mfma<false><<<sage_blocks, 256, 0, stream>>>(x,  row_ptr, csr_src, invdeg, wf1,
                                                      b1, g1, be1, hA, gb, gsum, gmax, gcnt);
    sage_mfma<false><<<sage_blocks, 256, 0, stream>>>(hA, row_ptr, csr_src, invdeg, wf2,
                                                      b2, g2, be2, hB, gb, gsum, gmax, gcnt);
    sage_mfma<true><<<sage_blocks, 256, 0, stream>>>(hB, row_ptr, csr_src, invdeg, wf3,
                                                     b3, g3, be3, hA, gb, gsum, gmax, gcnt);

    // ---- readout ----
    readout_kernel<<<N_GRAPHS, 256, 0, stream>>>(gsum, gmax, gcnt, Wr1, br1, Wr2, br2, (float*)d_out);
}

// Round 11
// 343.122 us; speedup vs baseline: 4.1757x; 1.0153x over previous
//
#include <hip/hip_runtime.h>
#include <hip/hip_bf16.h>

#define N_NODES 100000
#define N_EDGES 600000
#define HID 128
#define OUT_DIM 256
#define N_GRAPHS 256
#define BN 32            // nodes per block in fused SAGE kernel
#define LDA2 132         // smA row stride in floats
#define SCAN_B 512
#define SCAN_NB ((N_NODES + SCAN_B) / SCAN_B)

typedef __attribute__((ext_vector_type(8))) __bf16 bf16x8;
typedef __attribute__((ext_vector_type(4))) float f32x4;

__device__ inline f32x4 mfma16(bf16x8 a, bf16x8 b, f32x4 c) {
    return __builtin_amdgcn_mfma_f32_16x16x32_bf16(a, b, c, 0, 0, 0);
}

__device__ inline unsigned short bf_bits(__bf16 b) {
    union { __bf16 b; unsigned short u; } x; x.b = b; return x.u;
}

// ---------------- degree count + (blocks 0..383) weight prep ----------------
// Weight prep: stacked [Wl;Wr] -> fragment-major bf16 hi/lo, identical layout to r10:
//   p*32768 + ks*4096 + nf*512 + lane*8 + j ; value = W[k=ks*32+(lane>>4)*8+j][c=nf*16+(lane&15)]
__global__ void count_prep_kernel(
    const int* __restrict__ dst, int* __restrict__ deg,
    const float* __restrict__ W1l, const float* __restrict__ W1r,
    const float* __restrict__ W2l, const float* __restrict__ W2r,
    const float* __restrict__ W3l, const float* __restrict__ W3r,
    unsigned short* __restrict__ wf1, unsigned short* __restrict__ wf2,
    unsigned short* __restrict__ wf3)
{
    int e = blockIdx.x * blockDim.x + threadIdx.x;
    if (e < N_EDGES) atomicAdd(&deg[dst[e]], 1);

    if (blockIdx.x < 384) {
        int set = blockIdx.x >> 7;
        const float* Wl = (set == 0) ? W1l : (set == 1) ? W2l : W3l;
        const float* Wr = (set == 0) ? W1r : (set == 1) ? W2r : W3r;
        unsigned short* wf = (set == 0) ? wf1 : (set == 1) ? wf2 : wf3;

        int flat = (blockIdx.x & 127) * 256 + threadIdx.x;   // 32768 per set
        int j  = flat & 7;
        int l  = (flat >> 3) & 63;
        int nf = (flat >> 9) & 7;
        int ks = flat >> 12;
        int k = ks * 32 + ((l >> 4) << 3) + j;
        int c = nf * 16 + (l & 15);
        float v = (k < HID) ? Wl[k * HID + c] : Wr[(k - HID) * HID + c];
        __bf16 hi = (__bf16)v;
        __bf16 lo = (__bf16)(v - (float)hi);
        wf[flat]         = bf_bits(hi);
        wf[32768 + flat] = bf_bits(lo);
    }
}

// ---------------- block-level exclusive scan ----------------
__global__ __launch_bounds__(SCAN_B) void scan1_kernel(
    const int* __restrict__ deg, int* __restrict__ part, int* __restrict__ bsum)
{
    __shared__ int s[SCAN_B];
    int t = threadIdx.x;
    int i = blockIdx.x * SCAN_B + t;
    int v = (i < N_NODES) ? deg[i] : 0;
    s[t] = v;
    __syncthreads();
    #pragma unroll
    for (int off = 1; off < SCAN_B; off <<= 1) {
        int x = (t >= off) ? s[t - off] : 0;
        __syncthreads();
        s[t] += x;
        __syncthreads();
    }
    part[i] = s[t] - v;
    if (t == SCAN_B - 1) bsum[blockIdx.x] = s[t];
}

// ---------------- finalize row_ptr/cursor/invdeg; block offset computed inline ----------------
// boff[blockIdx.x] = sum_{b < blockIdx.x} bsum[b]  (exact integer sum, replaces scan2)
__global__ __launch_bounds__(SCAN_B) void scan3_kernel(
    const int* __restrict__ part, const int* __restrict__ bsum,
    const int* __restrict__ deg,
    int* __restrict__ row_ptr, int* __restrict__ cursor, float* __restrict__ invdeg)
{
    __shared__ int sm[256];
    int t = threadIdx.x;
    if (t < 256) {
        int v = (t < SCAN_NB && t < (int)blockIdx.x) ? bsum[t] : 0;
        sm[t] = v;
    }
    __syncthreads();
    #pragma unroll
    for (int off = 128; off >= 1; off >>= 1) {
        if (t < off) sm[t] += sm[t + off];
        __syncthreads();
    }
    int base = sm[0];

    int i = blockIdx.x * SCAN_B + t;
    int rp = part[i] + base;
    if (i <= N_NODES) row_ptr[i] = rp;
    if (i < N_NODES) {
        cursor[i] = rp;
        invdeg[i] = 1.0f / (float)max(deg[i], 1);
    }
}

// fill CSR; also zero the pool accumulators (needed before layer-3's fused pool)
__global__ void fill_kernel(const int* __restrict__ src, const int* __restrict__ dst,
                            int* __restrict__ cursor, int* __restrict__ csr_src,
                            float* __restrict__ gsum, float* __restrict__ gmax,
                            float* __restrict__ gcnt)
{
    int e = blockIdx.x * blockDim.x + threadIdx.x;
    if (e < N_GRAPHS * HID) { gsum[e] = 0.f; gmax[e] = 0.f; }
    if (e < N_GRAPHS) gcnt[e] = 0.f;
    if (e < N_EDGES) {
        int t = dst[e];
        int pos = atomicAdd(&cursor[t], 1);
        csr_src[pos] = src[e];
    }
}

// ---------------- fused gather + split-bf16 MFMA GEMM + LayerNorm + ReLU (+pool) ----------------
// BYTE-IDENTICAL to the round-10 passing kernel (absmax 4.88e-4). Do not reorder arithmetic.
template<bool LAST>
__global__ __launch_bounds__(256, 8) void sage_mfma(
    const float* __restrict__ h_in,
    const int* __restrict__ row_ptr, const int* __restrict__ csr_src,
    const float* __restrict__ invdeg,
    const unsigned short* __restrict__ wf,
    const float* __restrict__ bias, const float* __restrict__ gamma,
    const float* __restrict__ beta,
    float* __restrict__ h_out,
    const int* __restrict__ gb,
    float* __restrict__ gsum, float* __restrict__ gmax, float* __restrict__ gcnt)
{
    __shared__ float smA[BN * LDA2];         // 16.9 KB: agg means -> (LAST) post-LN values
    __shared__ float lnred[BN][4][2];
    __shared__ int gbs[BN];

    const int tid  = threadIdx.x;
    const int lane = tid & 63;
    const int w    = tid >> 6;
    const int lq   = lane & 15;
    const int lg   = lane >> 4;
    const int node0 = blockIdx.x * BN;

    if (LAST && tid < BN) gbs[tid] = gb[node0 + tid];

    // ---- gather neighbor mean into smA[n][0..127] ----
    // half-wave per node (32 lanes x f32x4 = full 512B row per edge); the half-wave's
    // 4 nodes processed with hoisted index setup (4 independent index chains in flight).
    // VERIFIED structure (round-6/round-10 bench): loads only issued for valid slots.
    {
        const int hw = tid >> 5;             // half-wave id 0..7
        const int hl = tid & 31;
        const int d0 = hl << 2;

        int r0a[4], dga[4], idxa[4];
        float inva[4];
        #pragma unroll
        for (int i = 0; i < 4; ++i) {
            int node = node0 + hw * 4 + i;
            int rp0 = row_ptr[node];
            int rp1 = row_ptr[node + 1];
            r0a[i] = rp0;
            dga[i] = rp1 - rp0;
            idxa[i] = csr_src[min(rp0 + hl, N_EDGES - 1)];
            inva[i] = invdeg[node];
        }

        #pragma unroll
        for (int i = 0; i < 4; ++i) {
            int n = hw * 4 + i;
            int deg = dga[i];
            int dc = min(deg, 32);
            f32x4 a0 = {0.f, 0.f, 0.f, 0.f}, a1 = a0, a2 = a0, a3 = a0;
            int s = 0;
            for (; s + 3 < dc; s += 4) {     // 4 independent loads per step
                int i0 = __shfl(idxa[i], s,     32);
                int i1 = __shfl(idxa[i], s + 1, 32);
                int i2 = __shfl(idxa[i], s + 2, 32);
                int i3 = __shfl(idxa[i], s + 3, 32);
                a0 += *(const f32x4*)(h_in + (size_t)i0 * HID + d0);
                a1 += *(const f32x4*)(h_in + (size_t)i1 * HID + d0);
                a2 += *(const f32x4*)(h_in + (size_t)i2 * HID + d0);
                a3 += *(const f32x4*)(h_in + (size_t)i3 * HID + d0);
            }
            if (s < dc) {                     // tail 1..3, rotating accumulators
                int i0 = __shfl(idxa[i], s, 32);
                a0 += *(const f32x4*)(h_in + (size_t)i0 * HID + d0);
                if (s + 1 < dc) {
                    int i1 = __shfl(idxa[i], s + 1, 32);
                    a1 += *(const f32x4*)(h_in + (size_t)i1 * HID + d0);
                }
                if (s + 2 < dc) {
                    int i2 = __shfl(idxa[i], s + 2, 32);
                    a2 += *(const f32x4*)(h_in + (size_t)i2 * HID + d0);
                }
            }
            for (int t2 = 32; t2 < deg; ++t2) {   // P(deg>32) ~ 1e-12
                int i0 = csr_src[r0a[i] + t2];
                a0 += *(const f32x4*)(h_in + (size_t)i0 * HID + d0);
            }
            f32x4 a = (a0 + a1) + (a2 + a3);
            a *= inva[i];
            *(f32x4*)&smA[n * LDA2 + d0] = a;
        }
    }
    __syncthreads();

    // ---- split-bf16 MFMA GEMM: out[32 x 128] = [agg|root][32 x 256] @ W[256 x 128] ----
    // agg half (ks 0..3) from LDS; root half (ks 4..7) straight from global.
    // FULL 4-term product (ahi+alo)(bhi+blo): per-product error ~2^-18 relative.
    const int nf0 = w * 2;
    const int col0 = nf0 * 16 + lq;          // = w*32 + lq
    const int col1 = col0 + 16;

    f32x4 acc[2][2];
    {
        float b0 = bias[col0], b1 = bias[col1];
        #pragma unroll
        for (int m = 0; m < 2; ++m) {
            acc[m][0] = (f32x4){b0, b0, b0, b0};
            acc[m][1] = (f32x4){b1, b1, b1, b1};
        }
    }

    const bf16x8* wfv = (const bf16x8*)wf;
    #pragma unroll 2
    for (int ks = 0; ks < 8; ++ks) {
        int base = (ks << 9) + nf0 * 64 + lane;      // ushort8 units
        bf16x8 bh0 = wfv[base];
        bf16x8 bh1 = wfv[base + 64];
        bf16x8 bl0 = wfv[base + 4096];
        bf16x8 bl1 = wfv[base + 4096 + 64];
        #pragma unroll
        for (int m = 0; m < 2; ++m) {
            float4 a0, a1;
            if (ks < 4) {
                const float* ap = &smA[(m * 16 + lq) * LDA2 + (ks << 5) + (lg << 3)];
                a0 = *(const float4*)ap;
                a1 = *(const float4*)(ap + 4);
            } else {
                const float* rp = h_in + (size_t)(node0 + m * 16 + lq) * HID
                                + ((ks - 4) << 5) + (lg << 3);
                a0 = *(const float4*)rp;
                a1 = *(const float4*)(rp + 4);
            }
            float av[8] = {a0.x, a0.y, a0.z, a0.w, a1.x, a1.y, a1.z, a1.w};
            bf16x8 ahi, alo;
            #pragma unroll
            for (int j = 0; j < 8; ++j) {
                __bf16 h = (__bf16)av[j];
                ahi[j] = h;
                alo[j] = (__bf16)(av[j] - (float)h);
            }
            acc[m][0] = mfma16(ahi, bh0, acc[m][0]);
            acc[m][0] = mfma16(alo, bh0, acc[m][0]);
            acc[m][0] = mfma16(ahi, bl0, acc[m][0]);
            acc[m][0] = mfma16(alo, bl0, acc[m][0]);
            acc[m][1] = mfma16(ahi, bh1, acc[m][1]);
            acc[m][1] = mfma16(alo, bh1, acc[m][1]);
            acc[m][1] = mfma16(ahi, bl1, acc[m][1]);
            acc[m][1] = mfma16(alo, bl1, acc[m][1]);
        }
    }

    // ---- LayerNorm partials: value (m, r) sits at node m*16+lg*4+r ----
    #pragma unroll
    for (int m = 0; m < 2; ++m) {
        #pragma unroll
        for (int r = 0; r < 4; ++r) {
            float pv = acc[m][0][r] + acc[m][1][r];
            float qv = acc[m][0][r] * acc[m][0][r] + acc[m][1][r] * acc[m][1][r];
            #pragma unroll
            for (int off = 8; off >= 1; off >>= 1) {
                pv += __shfl_xor(pv, off, 64);
                qv += __shfl_xor(qv, off, 64);
            }
            if (lq == 0) {
                int n = m * 16 + lg * 4 + r;
                lnred[n][w][0] = pv;
                lnred[n][w][1] = qv;
            }
        }
    }
    __syncthreads();   // also guarantees all smA (agg) reads are done

    // ---- finalize LN + ReLU; store to global (layers 1,2) or LDS (layer 3) ----
    float g0 = gamma[col0], g1 = gamma[col1];
    float be0 = beta[col0], be1 = beta[col1];
    #pragma unroll
    for (int m = 0; m < 2; ++m) {
        #pragma unroll
        for (int r = 0; r < 4; ++r) {
            int n = m * 16 + lg * 4 + r;
            float p = lnred[n][0][0] + lnred[n][1][0] + lnred[n][2][0] + lnred[n][3][0];
            float q = lnred[n][0][1] + lnred[n][1][1] + lnred[n][2][1] + lnred[n][3][1];
            float mu  = p * (1.0f / HID);
            float var = q * (1.0f / HID) - mu * mu;
            // Newton-refined rsqrt: v_rsq_f32 is ~2^-12 approx; one step -> ~2^-23
            float xv = var + 1e-5f;
            float rs = rsqrtf(xv);
            rs = rs * (1.5f - 0.5f * xv * rs * rs);
            float o0 = fmaxf((acc[m][0][r] - mu) * rs * g0 + be0, 0.f);
            float o1 = fmaxf((acc[m][1][r] - mu) * rs * g1 + be1, 0.f);
            if (LAST) {
                smA[n * LDA2 + col0] = o0;
                smA[n * LDA2 + col1] = o1;
            } else {
                int node = node0 + n;
                h_out[(size_t)node * HID + col0] = o0;
                h_out[(size_t)node * HID + col1] = o1;
            }
        }
    }

    if (LAST) {
        __syncthreads();
        // block-level segmented mean/max pool over the 32 sorted nodes
        int colp = tid & 127;
        int nst = (tid >> 7) * 16, nen = nst + 16;
        int curg = gbs[nst];
        float s = 0.f, mx = 0.f;
        int c = 0;
        for (int n2 = nst; n2 < nen; ++n2) {
            int g = gbs[n2];
            if (g != curg) {
                atomicAdd(&gsum[curg * HID + colp], s);
                atomicMax((int*)&gmax[curg * HID + colp], __float_as_int(mx));
                if (colp == 0) atomicAdd(&gcnt[curg], (float)c);
                curg = g; s = 0.f; mx = 0.f; c = 0;
            }
            float v = smA[n2 * LDA2 + colp];
            s += v;
            mx = fmaxf(mx, v);   // post-ReLU: v >= 0, init 0 safe
            ++c;
        }
        atomicAdd(&gsum[curg * HID + colp], s);
        atomicMax((int*)&gmax[curg * HID + colp], __float_as_int(mx));
        if (colp == 0) atomicAdd(&gcnt[curg], (float)c);
    }
}

// ---------------- readout MLP + L2 normalize ----------------
__global__ __launch_bounds__(256) void readout_kernel(
    const float* __restrict__ gsum, const float* __restrict__ gmax,
    const float* __restrict__ gcnt,
    const float* __restrict__ Wr1, const float* __restrict__ br1,
    const float* __restrict__ Wr2, const float* __restrict__ br2,
    float* __restrict__ out)
{
    __shared__ float pooled[2 * HID];
    __shared__ float hid[HID];
    __shared__ float red[4];

    int g = blockIdx.x, tid = threadIdx.x;

    if (tid < HID) {
        float n = fmaxf(gcnt[g], 1.0f);
        pooled[tid] = gsum[g * HID + tid] / n;
    } else {
        pooled[tid] = gmax[g * HID + (tid - HID)];
    }
    __syncthreads();

    if (tid < HID) {
        float a = br1[tid];
        for (int k = 0; k < 2 * HID; ++k)
            a += pooled[k] * Wr1[k * HID + tid];
        hid[tid] = fmaxf(a, 0.0f);
    }
    __syncthreads();

    float a = br2[tid];
    for (int k = 0; k < HID; ++k)
        a += hid[k] * Wr2[k * OUT_DIM + tid];

    float ss = a * a;
    #pragma unroll
    for (int off = 32; off >= 1; off >>= 1) ss += __shfl_xor(ss, off, 64);
    int wv = tid >> 6, lane = tid & 63;
    if (lane == 0) red[wv] = ss;
    __syncthreads();
    float tot = red[0] + red[1] + red[2] + red[3];
    float nrm = fmaxf(sqrtf(tot), 1e-12f);
    out[g * OUT_DIM + tid] = a / nrm;
}

extern "C" void kernel_launch(void* const* d_in, const int* in_sizes, int n_in,
                              void* d_out, int out_size, void* d_ws, size_t ws_size,
                              hipStream_t stream) {
    const float* x   = (const float*)d_in[0];
    const int*   ei  = (const int*)d_in[1];
    const int*   gb  = (const int*)d_in[2];
    const float* W1l = (const float*)d_in[3];
    const float* W1r = (const float*)d_in[4];
    const float* b1  = (const float*)d_in[5];
    const float* g1  = (const float*)d_in[6];
    const float* be1 = (const float*)d_in[7];
    const float* W2l = (const float*)d_in[8];
    const float* W2r = (const float*)d_in[9];
    const float* b2  = (const float*)d_in[10];
    const float* g2  = (const float*)d_in[11];
    const float* be2 = (const float*)d_in[12];
    const float* W3l = (const float*)d_in[13];
    const float* W3r = (const float*)d_in[14];
    const float* b3  = (const float*)d_in[15];
    const float* g3  = (const float*)d_in[16];
    const float* be3 = (const float*)d_in[17];
    const float* Wr1 = (const float*)d_in[18];
    const float* br1 = (const float*)d_in[19];
    const float* Wr2 = (const float*)d_in[20];
    const float* br2 = (const float*)d_in[21];

    const int* src = ei;
    const int* dst = ei + N_EDGES;

    char* ws = (char*)d_ws;
    size_t off = 0;
    auto alloc = [&](size_t bytes) -> void* {
        void* p = ws + off;
        off += (bytes + 255) & ~(size_t)255;
        return p;
    };
    float* hA      = (float*)alloc((size_t)N_NODES * HID * 4);
    float* hB      = (float*)alloc((size_t)N_NODES * HID * 4);
    int*   deg     = (int*)alloc((size_t)N_NODES * 4);
    int*   part    = (int*)alloc((size_t)SCAN_NB * SCAN_B * 4);
    int*   bsum    = (int*)alloc((size_t)SCAN_NB * 4);
    int*   row_ptr = (int*)alloc((size_t)(N_NODES + 1) * 4);
    int*   cursor  = (int*)alloc((size_t)N_NODES * 4);
    float* invdeg  = (float*)alloc((size_t)N_NODES * 4);
    int*   csr_src = (int*)alloc((size_t)N_EDGES * 4);
    float* gsum    = (float*)alloc((size_t)N_GRAPHS * HID * 4);
    float* gmax    = (float*)alloc((size_t)N_GRAPHS * HID * 4);
    float* gcnt    = (float*)alloc((size_t)N_GRAPHS * 4);
    unsigned short* wf1 = (unsigned short*)alloc(65536 * 2);
    unsigned short* wf2 = (unsigned short*)alloc(65536 * 2);
    unsigned short* wf3 = (unsigned short*)alloc(65536 * 2);

    // ---- build CSR (once) + weight prep (fused) + pool-buffer zeroing ----
    hipMemsetAsync(deg, 0, (size_t)N_NODES * 4, stream);
    count_prep_kernel<<<(N_EDGES + 255) / 256, 256, 0, stream>>>(
        dst, deg, W1l, W1r, W2l, W2r, W3l, W3r, wf1, wf2, wf3);
    scan1_kernel<<<SCAN_NB, SCAN_B, 0, stream>>>(deg, part, bsum);
    scan3_kernel<<<SCAN_NB, SCAN_B, 0, stream>>>(part, bsum, deg, row_ptr, cursor, invdeg);
    fill_kernel<<<(N_EDGES + 255) / 256, 256, 0, stream>>>(src, dst, cursor, csr_src,
                                                           gsum, gmax, gcnt);

    const int sage_blocks = N_NODES / BN;   // 3125, exact

    // ---- 3 fused SAGE layers (layer 3 fuses the pool) ----
    sage_mfma<false><<<sage_blocks, 256, 0, stream>>>(x,  row_ptr, csr_src, invdeg, wf1,
                                                      b1, g1, be1, hA, gb, gsum, gmax, gcnt);
    sage_mfma<false><<<sage_blocks, 256, 0, stream>>>(hA, row_ptr, csr_src, invdeg, wf2,
                                                      b2, g2, be2, hB, gb, gsum, gmax, gcnt);
    sage_mfma<true><<<sage_blocks, 256, 0, stream>>>(hB, row_ptr, csr_src, invdeg, wf3,
                                                     b3, g3, be3, hA, gb, gsum, gmax, gcnt);

    // ---- readout ----
    readout_kernel<<<N_GRAPHS, 256, 0, stream>>>(gsum, gmax, gcnt, Wr1, br1, Wr2, br2, (float*)d_out);
}